// Round 1
// baseline (461.385 us; speedup 1.0000x reference)
//
#include <hip/hip_runtime.h>

#define NPB 16  // nodes per block in transform kernels

// ---- Layer-1 transform: p = x@Wrel, buf = x@Wroot + b  (F=64 -> H=16) ----
__global__ __launch_bounds__(256) void k_transform1(
    const float* __restrict__ x, const float* __restrict__ Wrel,
    const float* __restrict__ Wroot, const float* __restrict__ bias,
    float* __restrict__ p, float* __restrict__ buf, int n_nodes)
{
    __shared__ float s_wrel[64 * 16];
    __shared__ float s_wroot[64 * 16];
    __shared__ float s_b[16];
    __shared__ float s_x[NPB * 68];  // pad 64->68: keeps float4 align, kills bank conflicts

    const int t = threadIdx.x;
    for (int i = t; i < 1024; i += 256) { s_wrel[i] = Wrel[i]; s_wroot[i] = Wroot[i]; }
    if (t < 16) s_b[t] = bias[t];

    const int node0 = blockIdx.x * NPB;
    {   // stage 16 rows x 64 floats, one float4 per thread, fully coalesced
        const int r = t >> 4, q = t & 15;
        const int node = node0 + r;
        if (node < n_nodes) {
            const float4 v = *(const float4*)(x + (size_t)node * 64 + q * 4);
            s_x[r * 68 + q * 4 + 0] = v.x;
            s_x[r * 68 + q * 4 + 1] = v.y;
            s_x[r * 68 + q * 4 + 2] = v.z;
            s_x[r * 68 + q * 4 + 3] = v.w;
        }
    }
    __syncthreads();

    const int n = t >> 4, o = t & 15;
    const int node = node0 + n;
    float accr = 0.f, acco = 0.f;
    const float* xr = s_x + n * 68;
#pragma unroll
    for (int k = 0; k < 64; ++k) {
        const float xv = xr[k];
        accr = fmaf(xv, s_wrel[k * 16 + o], accr);
        acco = fmaf(xv, s_wroot[k * 16 + o], acco);
    }
    if (node < n_nodes) {
        p[(size_t)node * 16 + o]   = accr;
        buf[(size_t)node * 16 + o] = acco + s_b[o];
    }
}

// ---- Layer-2 transform: relu on input, p = h@Wrel, buf = h@Wroot + b (16->16) ----
__global__ __launch_bounds__(256) void k_transform2(
    const float* __restrict__ hin, const float* __restrict__ Wrel,
    const float* __restrict__ Wroot, const float* __restrict__ bias,
    float* __restrict__ p, float* __restrict__ buf, int n_nodes)
{
    __shared__ float s_wrel[256];
    __shared__ float s_wroot[256];
    __shared__ float s_b[16];
    __shared__ float s_h[NPB * 20];  // pad 16->20

    const int t = threadIdx.x;
    s_wrel[t] = Wrel[t];
    s_wroot[t] = Wroot[t];
    if (t < 16) s_b[t] = bias[t];

    const int node0 = blockIdx.x * NPB;
    if (t < 64) {  // 16 rows x 16 floats = 64 float4
        const int r = t >> 2, q = t & 3;
        const int node = node0 + r;
        if (node < n_nodes) {
            const float4 v = *(const float4*)(hin + (size_t)node * 16 + q * 4);
            s_h[r * 20 + q * 4 + 0] = fmaxf(v.x, 0.f);   // relu here
            s_h[r * 20 + q * 4 + 1] = fmaxf(v.y, 0.f);
            s_h[r * 20 + q * 4 + 2] = fmaxf(v.z, 0.f);
            s_h[r * 20 + q * 4 + 3] = fmaxf(v.w, 0.f);
        }
    }
    __syncthreads();

    const int n = t >> 4, o = t & 15;
    const int node = node0 + n;
    float accr = 0.f, acco = 0.f;
    const float* hr = s_h + n * 20;
#pragma unroll
    for (int k = 0; k < 16; ++k) {
        const float hv = hr[k];
        accr = fmaf(hv, s_wrel[k * 16 + o], accr);
        acco = fmaf(hv, s_wroot[k * 16 + o], acco);
    }
    if (node < n_nodes) {
        p[(size_t)node * 16 + o]   = accr;
        buf[(size_t)node * 16 + o] = acco + s_b[o];
    }
}

// ---- Edge scatter: buf[dst] += p[src], 16 floats per edge, 4 per thread ----
__global__ __launch_bounds__(256) void k_scatter(
    const int* __restrict__ src, const int* __restrict__ dst,
    const float* __restrict__ p, float* __restrict__ buf, int n_edges)
{
    const int idx = blockIdx.x * 256 + threadIdx.x;
    if (idx >= n_edges * 4) return;
    const int e = idx >> 2, q = idx & 3;
    const int s = src[e], d = dst[e];
    const float4 v = *(const float4*)(p + (size_t)s * 16 + q * 4);
    float* bp = buf + (size_t)d * 16 + q * 4;
    unsafeAtomicAdd(bp + 0, v.x);
    unsafeAtomicAdd(bp + 1, v.y);
    unsafeAtomicAdd(bp + 2, v.z);
    unsafeAtomicAdd(bp + 3, v.w);
}

// ---- Mean-pool partial sums: LDS-privatized per-graph accumulation ----
__global__ __launch_bounds__(256) void k_pool(
    const float* __restrict__ h, const int* __restrict__ batch,
    float* __restrict__ gsum, float* __restrict__ gcnt, int n_nodes)
{
    __shared__ float s_sum[64 * 16];
    __shared__ float s_cnt[64];
    const int t = threadIdx.x;
    for (int i = t; i < 1024; i += 256) s_sum[i] = 0.f;
    if (t < 64) s_cnt[t] = 0.f;
    __syncthreads();

    const int total = n_nodes * 16;
    const int stride = gridDim.x * 256;
    for (int idx = blockIdx.x * 256 + t; idx < total; idx += stride) {
        const int n = idx >> 4, f = idx & 15;
        const int g = batch[n];
        unsafeAtomicAdd(&s_sum[g * 16 + f], h[idx]);
        if (f == 0) unsafeAtomicAdd(&s_cnt[g], 1.f);
    }
    __syncthreads();
    // sorted batch -> each block touches ~2 graphs; flush only nonzero slots
    for (int i = t; i < 1024; i += 256)
        if (s_sum[i] != 0.f) unsafeAtomicAdd(&gsum[i], s_sum[i]);
    if (t < 64 && s_cnt[t] != 0.f) unsafeAtomicAdd(&gcnt[t], s_cnt[t]);
}

// ---- Final head: out[g] = (gsum[g]/max(cnt,1)) . Wlin + blin ----
__global__ void k_finalize(
    const float* __restrict__ gsum, const float* __restrict__ gcnt,
    const float* __restrict__ Wlin, const float* __restrict__ blin,
    float* __restrict__ out, int n_graphs)
{
    const int g = threadIdx.x;
    if (g >= n_graphs) return;
    const float c = fmaxf(gcnt[g], 1.f);
    float acc = 0.f;
#pragma unroll
    for (int f = 0; f < 16; ++f) acc = fmaf(gsum[g * 16 + f], Wlin[f], acc);
    out[g] = acc / c + blin[0];
}

extern "C" void kernel_launch(void* const* d_in, const int* in_sizes, int n_in,
                              void* d_out, int out_size, void* d_ws, size_t ws_size,
                              hipStream_t stream) {
    const float* x       = (const float*)d_in[0];
    const int*   ei      = (const int*)d_in[1];
    const int*   batch   = (const int*)d_in[2];
    const float* W1_rel  = (const float*)d_in[3];
    const float* W1_root = (const float*)d_in[4];
    const float* b1      = (const float*)d_in[5];
    const float* W2_rel  = (const float*)d_in[6];
    const float* W2_root = (const float*)d_in[7];
    const float* b2      = (const float*)d_in[8];
    const float* Wlin    = (const float*)d_in[9];
    const float* blin    = (const float*)d_in[10];
    float* out = (float*)d_out;

    const int n_nodes  = in_sizes[0] / 64;
    const int n_edges  = in_sizes[1] / 2;
    const int n_graphs = out_size;

    float* ws   = (float*)d_ws;
    float* p    = ws;                          // N*16  (p1, reused as p2)
    float* buf1 = ws + (size_t)n_nodes * 16;   // N*16
    float* buf2 = ws + (size_t)n_nodes * 32;   // N*16
    float* gsum = ws + (size_t)n_nodes * 48;   // G*16
    float* gcnt = gsum + (size_t)n_graphs * 16;// G

    const int* src = ei;
    const int* dst = ei + n_edges;

    hipMemsetAsync(gsum, 0, (size_t)(n_graphs * 17) * sizeof(float), stream);

    const int nb = (n_nodes + NPB - 1) / NPB;
    const int eb = (n_edges * 4 + 255) / 256;

    k_transform1<<<nb, 256, 0, stream>>>(x, W1_rel, W1_root, b1, p, buf1, n_nodes);
    k_scatter  <<<eb, 256, 0, stream>>>(src, dst, p, buf1, n_edges);
    k_transform2<<<nb, 256, 0, stream>>>(buf1, W2_rel, W2_root, b2, p, buf2, n_nodes);
    k_scatter  <<<eb, 256, 0, stream>>>(src, dst, p, buf2, n_edges);
    k_pool     <<<400, 256, 0, stream>>>(buf2, batch, gsum, gcnt, n_nodes);
    k_finalize <<<1, 64, 0, stream>>>(gsum, gcnt, Wlin, blin, out, n_graphs);
}

// Round 2
// 263.907 us; speedup vs baseline: 1.7483x; 1.7483x over previous
//
#include <hip/hip_runtime.h>

// ============ CSR build ============

__global__ __launch_bounds__(256) void k_hist(
    const int* __restrict__ dst, int* __restrict__ deg, int n_edges)
{
    const int e = blockIdx.x * 256 + threadIdx.x;
    if (e < n_edges) atomicAdd(&deg[dst[e]], 1);
}

__global__ __launch_bounds__(256) void k_scan1(
    const int* __restrict__ deg, int* __restrict__ bsum, int n)
{
    __shared__ int s[256];
    const int t = threadIdx.x;
    const int i = blockIdx.x * 256 + t;
    s[t] = (i < n) ? deg[i] : 0;
    __syncthreads();
    for (int off = 128; off > 0; off >>= 1) {
        if (t < off) s[t] += s[t + off];
        __syncthreads();
    }
    if (t == 0) bsum[blockIdx.x] = s[0];
}

__global__ __launch_bounds__(512) void k_scan2(
    const int* __restrict__ bsum, int* __restrict__ boff, int nb)
{
    __shared__ int s[512];
    const int t = threadIdx.x;
    const int v = (t < nb) ? bsum[t] : 0;
    s[t] = v;
    __syncthreads();
    for (int off = 1; off < 512; off <<= 1) {
        int x = s[t];
        if (t >= off) x += s[t - off];
        __syncthreads();
        s[t] = x;
        __syncthreads();
    }
    if (t < nb) boff[t] = s[t] - v;  // exclusive block offsets
}

__global__ __launch_bounds__(256) void k_scan3(
    const int* __restrict__ deg, const int* __restrict__ boff,
    int* __restrict__ rowptr, int* __restrict__ cursor, int n, int n_edges)
{
    __shared__ int s[256];
    const int t = threadIdx.x;
    const int i = blockIdx.x * 256 + t;
    const int v = (i < n) ? deg[i] : 0;
    s[t] = v;
    __syncthreads();
    for (int off = 1; off < 256; off <<= 1) {
        int x = s[t];
        if (t >= off) x += s[t - off];
        __syncthreads();
        s[t] = x;
        __syncthreads();
    }
    const int excl = s[t] - v + boff[blockIdx.x];
    if (i < n) { rowptr[i] = excl; cursor[i] = excl; }
    if (i == 0) rowptr[n] = n_edges;
}

__global__ __launch_bounds__(256) void k_reorder(
    const int* __restrict__ src, const int* __restrict__ dst,
    int* __restrict__ cursor, int* __restrict__ csr_src, int n_edges)
{
    const int e = blockIdx.x * 256 + threadIdx.x;
    if (e < n_edges) {
        const int pos = atomicAdd(&cursor[dst[e]], 1);
        csr_src[pos] = src[e];
    }
}

// ============ Layer-1 transform: p = x@Wrel, buf = x@Wroot + b (64->16) ============
// 64 nodes/block; thread (o = t&15, ng = t>>4) computes 4 nodes x 1 output,
// all LDS traffic via ds_read_b128 (weights transposed, rows padded).
__global__ __launch_bounds__(256) void k_transform1(
    const float* __restrict__ x, const float* __restrict__ Wrel,
    const float* __restrict__ Wroot, const float* __restrict__ bias,
    float* __restrict__ p, float* __restrict__ buf, int n_nodes)
{
    __shared__ float s_x[64 * 68];      // 64 rows, pad 64->68 floats
    __shared__ float s_wrT[16 * 68];    // Wrel transposed [o][k], pad
    __shared__ float s_woT[16 * 68];
    __shared__ float s_b[16];

    const int t = threadIdx.x;
    for (int i = t; i < 1024; i += 256) {
        const int k = i >> 4, o = i & 15;
        s_wrT[o * 68 + k] = Wrel[i];
        s_woT[o * 68 + k] = Wroot[i];
    }
    if (t < 16) s_b[t] = bias[t];

    const int node0 = blockIdx.x * 64;
    for (int i = t; i < 1024; i += 256) {   // 64 rows x 16 float4
        const int r = i >> 4, c = i & 15;
        const int node = node0 + r;
        if (node < n_nodes) {
            const float4 v = *(const float4*)(x + (size_t)node * 64 + c * 4);
            *(float4*)&s_x[r * 68 + c * 4] = v;
        }
    }
    __syncthreads();

    const int o = t & 15, ng = t >> 4;
    float accr[4] = {0.f, 0.f, 0.f, 0.f};
    float acco[4] = {0.f, 0.f, 0.f, 0.f};
#pragma unroll
    for (int k4 = 0; k4 < 16; ++k4) {
        const float4 wr = *(const float4*)&s_wrT[o * 68 + k4 * 4];
        const float4 wo = *(const float4*)&s_woT[o * 68 + k4 * 4];
#pragma unroll
        for (int j = 0; j < 4; ++j) {
            const float4 xv = *(const float4*)&s_x[(ng * 4 + j) * 68 + k4 * 4];
            accr[j] = fmaf(xv.x, wr.x, fmaf(xv.y, wr.y, fmaf(xv.z, wr.z, fmaf(xv.w, wr.w, accr[j]))));
            acco[j] = fmaf(xv.x, wo.x, fmaf(xv.y, wo.y, fmaf(xv.z, wo.z, fmaf(xv.w, wo.w, acco[j]))));
        }
    }
#pragma unroll
    for (int j = 0; j < 4; ++j) {
        const int node = node0 + ng * 4 + j;
        if (node < n_nodes) {
            p[(size_t)node * 16 + o]   = accr[j];
            buf[(size_t)node * 16 + o] = acco[j] + s_b[o];
        }
    }
}

// ============ Layer-2 transform (16->16), relu on input, IN-PLACE on buf ============
__global__ __launch_bounds__(256) void k_transform2(
    float* __restrict__ buf, const float* __restrict__ Wrel,
    const float* __restrict__ Wroot, const float* __restrict__ bias,
    float* __restrict__ p, int n_nodes)
{
    __shared__ float s_h[64 * 20];
    __shared__ float s_wrT[16 * 20];
    __shared__ float s_woT[16 * 20];
    __shared__ float s_b[16];

    const int t = threadIdx.x;
    if (t < 256) {
        const int k = t >> 4, o = t & 15;
        s_wrT[o * 20 + k] = Wrel[t];
        s_woT[o * 20 + k] = Wroot[t];
    }
    if (t < 16) s_b[t] = bias[t];

    const int node0 = blockIdx.x * 64;
    {   // 64 rows x 4 float4 = 256 loads, one per thread; relu at load
        const int r = t >> 2, c = t & 3;
        const int node = node0 + r;
        float4 v = make_float4(0.f, 0.f, 0.f, 0.f);
        if (node < n_nodes) v = *(const float4*)(buf + (size_t)node * 16 + c * 4);
        s_h[r * 20 + c * 4 + 0] = fmaxf(v.x, 0.f);
        s_h[r * 20 + c * 4 + 1] = fmaxf(v.y, 0.f);
        s_h[r * 20 + c * 4 + 2] = fmaxf(v.z, 0.f);
        s_h[r * 20 + c * 4 + 3] = fmaxf(v.w, 0.f);
    }
    __syncthreads();

    const int o = t & 15, ng = t >> 4;
    float accr[4] = {0.f, 0.f, 0.f, 0.f};
    float acco[4] = {0.f, 0.f, 0.f, 0.f};
#pragma unroll
    for (int k4 = 0; k4 < 4; ++k4) {
        const float4 wr = *(const float4*)&s_wrT[o * 20 + k4 * 4];
        const float4 wo = *(const float4*)&s_woT[o * 20 + k4 * 4];
#pragma unroll
        for (int j = 0; j < 4; ++j) {
            const float4 hv = *(const float4*)&s_h[(ng * 4 + j) * 20 + k4 * 4];
            accr[j] = fmaf(hv.x, wr.x, fmaf(hv.y, wr.y, fmaf(hv.z, wr.z, fmaf(hv.w, wr.w, accr[j]))));
            acco[j] = fmaf(hv.x, wo.x, fmaf(hv.y, wo.y, fmaf(hv.z, wo.z, fmaf(hv.w, wo.w, acco[j]))));
        }
    }
#pragma unroll
    for (int j = 0; j < 4; ++j) {
        const int node = node0 + ng * 4 + j;
        if (node < n_nodes) {
            p[(size_t)node * 16 + o]   = accr[j];
            buf[(size_t)node * 16 + o] = acco[j] + s_b[o];  // own row only: in-place safe
        }
    }
}

// ============ Gather: buf[i] += sum_{j in CSR(i)} p[csr_src[j]]  (no atomics) ============
__global__ __launch_bounds__(256) void k_gather(
    const float* __restrict__ p, const int* __restrict__ rowptr,
    const int* __restrict__ csr_src, float* __restrict__ buf, int n_nodes)
{
    const int idx = blockIdx.x * 256 + threadIdx.x;
    const int node = idx >> 2, q = idx & 3;
    if (node >= n_nodes) return;
    const int beg = rowptr[node], end = rowptr[node + 1];
    float4 acc = *(const float4*)(buf + (size_t)node * 16 + q * 4);
    int j = beg;
    for (; j + 2 <= end; j += 2) {   // unroll x2: both loads issue before adds
        const int s0 = csr_src[j], s1 = csr_src[j + 1];
        const float4 a = *(const float4*)(p + (size_t)s0 * 16 + q * 4);
        const float4 b = *(const float4*)(p + (size_t)s1 * 16 + q * 4);
        acc.x += a.x; acc.y += a.y; acc.z += a.z; acc.w += a.w;
        acc.x += b.x; acc.y += b.y; acc.z += b.z; acc.w += b.w;
    }
    if (j < end) {
        const int s0 = csr_src[j];
        const float4 a = *(const float4*)(p + (size_t)s0 * 16 + q * 4);
        acc.x += a.x; acc.y += a.y; acc.z += a.z; acc.w += a.w;
    }
    *(float4*)(buf + (size_t)node * 16 + q * 4) = acc;
}

// ============ Mean-pool partials ============
__global__ __launch_bounds__(256) void k_pool(
    const float* __restrict__ h, const int* __restrict__ batch,
    float* __restrict__ gsum, float* __restrict__ gcnt, int n_nodes)
{
    __shared__ float s_sum[64 * 16];
    __shared__ float s_cnt[64];
    const int t = threadIdx.x;
    for (int i = t; i < 1024; i += 256) s_sum[i] = 0.f;
    if (t < 64) s_cnt[t] = 0.f;
    __syncthreads();

    const int total = n_nodes * 16;
    const int stride = gridDim.x * 256;
    for (int idx = blockIdx.x * 256 + t; idx < total; idx += stride) {
        const int n = idx >> 4, f = idx & 15;
        const int g = batch[n];
        atomicAdd(&s_sum[g * 16 + f], h[idx]);
        if (f == 0) atomicAdd(&s_cnt[g], 1.f);
    }
    __syncthreads();
    for (int i = t; i < 1024; i += 256)
        if (s_sum[i] != 0.f) atomicAdd(&gsum[i], s_sum[i]);
    if (t < 64 && s_cnt[t] != 0.f) atomicAdd(&gcnt[t], s_cnt[t]);
}

__global__ void k_finalize(
    const float* __restrict__ gsum, const float* __restrict__ gcnt,
    const float* __restrict__ Wlin, const float* __restrict__ blin,
    float* __restrict__ out, int n_graphs)
{
    const int g = threadIdx.x;
    if (g >= n_graphs) return;
    const float c = fmaxf(gcnt[g], 1.f);
    float acc = 0.f;
#pragma unroll
    for (int f = 0; f < 16; ++f) acc = fmaf(gsum[g * 16 + f], Wlin[f], acc);
    out[g] = acc / c + blin[0];
}

extern "C" void kernel_launch(void* const* d_in, const int* in_sizes, int n_in,
                              void* d_out, int out_size, void* d_ws, size_t ws_size,
                              hipStream_t stream) {
    const float* x       = (const float*)d_in[0];
    const int*   ei      = (const int*)d_in[1];
    const int*   batch   = (const int*)d_in[2];
    const float* W1_rel  = (const float*)d_in[3];
    const float* W1_root = (const float*)d_in[4];
    const float* b1      = (const float*)d_in[5];
    const float* W2_rel  = (const float*)d_in[6];
    const float* W2_root = (const float*)d_in[7];
    const float* b2      = (const float*)d_in[8];
    const float* Wlin    = (const float*)d_in[9];
    const float* blin    = (const float*)d_in[10];
    float* out = (float*)d_out;

    const int N = in_sizes[0] / 64;
    const int E = in_sizes[1] / 2;
    const int G = out_size;
    const int NB = (N + 255) / 256;   // scan blocks (391 for N=100k; must be <=512)

    const int* src = ei;
    const int* dst = ei + E;

    // workspace layout (all 16B-aligned where needed)
    float* ws      = (float*)d_ws;
    float* p       = ws;                              // N*16
    float* buf1    = p + (size_t)N * 16;              // N*16
    int*   deg     = (int*)(buf1 + (size_t)N * 16);   // N      -- memset region start
    float* gsum    = (float*)(deg + N);               // G*16
    float* gcnt    = gsum + (size_t)G * 16;           // G      -- memset region end
    int*   rowptr  = (int*)(gcnt + G);                // N+1
    int*   cursor  = rowptr + N + 1;                  // N
    int*   bsum    = cursor + N;                      // NB
    int*   boff    = bsum + NB;                       // NB
    int*   csr_src = boff + NB;                       // E

    hipMemsetAsync(deg, 0, (size_t)(N + G * 16 + G) * sizeof(int), stream);

    const int eb = (E + 255) / 256;
    const int tb = (N + 63) / 64;
    const int gb = (N * 4 + 255) / 256;

    // CSR build (amortized over both layers)
    k_hist   <<<eb, 256, 0, stream>>>(dst, deg, E);
    k_scan1  <<<NB, 256, 0, stream>>>(deg, bsum, N);
    k_scan2  <<<1, 512, 0, stream>>>(bsum, boff, NB);
    k_scan3  <<<NB, 256, 0, stream>>>(deg, boff, rowptr, cursor, N, E);
    k_reorder<<<eb, 256, 0, stream>>>(src, dst, cursor, csr_src, E);

    // layer 1
    k_transform1<<<tb, 256, 0, stream>>>(x, W1_rel, W1_root, b1, p, buf1, N);
    k_gather    <<<gb, 256, 0, stream>>>(p, rowptr, csr_src, buf1, N);
    // layer 2 (in-place on buf1)
    k_transform2<<<tb, 256, 0, stream>>>(buf1, W2_rel, W2_root, b2, p, N);
    k_gather    <<<gb, 256, 0, stream>>>(p, rowptr, csr_src, buf1, N);
    // pool + head
    k_pool    <<<400, 256, 0, stream>>>(buf1, batch, gsum, gcnt, N);
    k_finalize<<<1, 64, 0, stream>>>(gsum, gcnt, Wlin, blin, out, G);
}

// Round 3
// 201.849 us; speedup vs baseline: 2.2858x; 1.3075x over previous
//
#include <hip/hip_runtime.h>

#define SLOT 24   // fixed slots per node; Poisson(8) P(deg>24) ~ 1e-7 -> overflow list ~empty

// ============ Phase 1 (fused): transform1 + slot-CSR fill ============
// blocks [0, tb)          : p1 = x@W1rel, r1 = x@W1root + b1   (64 nodes/block)
// blocks [tb, tb+fb)      : slot fill, 4 edges/thread for atomic ILP
__global__ __launch_bounds__(256) void k_phase1(
    const float* __restrict__ x, const float* __restrict__ Wrel,
    const float* __restrict__ Wroot, const float* __restrict__ bias,
    const int* __restrict__ src, const int* __restrict__ dst,
    float* __restrict__ p1, float* __restrict__ r1,
    int* __restrict__ cnt, int* __restrict__ slots,
    int* __restrict__ ovf_n, int* __restrict__ ovf_dst, int* __restrict__ ovf_src,
    int n_nodes, int n_edges, int tb)
{
    const int t = threadIdx.x;
    if ((int)blockIdx.x < tb) {
        // ---- transform1 ----
        __shared__ float s_x[64 * 68];
        __shared__ float s_wrT[16 * 68];
        __shared__ float s_woT[16 * 68];
        __shared__ float s_b[16];

        for (int i = t; i < 1024; i += 256) {
            const int k = i >> 4, o = i & 15;
            s_wrT[o * 68 + k] = Wrel[i];
            s_woT[o * 68 + k] = Wroot[i];
        }
        if (t < 16) s_b[t] = bias[t];

        const int node0 = blockIdx.x * 64;
        for (int i = t; i < 1024; i += 256) {   // 64 rows x 16 float4
            const int r = i >> 4, c = i & 15;
            const int node = node0 + r;
            if (node < n_nodes)
                *(float4*)&s_x[r * 68 + c * 4] =
                    *(const float4*)(x + (size_t)node * 64 + c * 4);
        }
        __syncthreads();

        const int o = t & 15, ng = t >> 4;
        float accr[4] = {0.f, 0.f, 0.f, 0.f};
        float acco[4] = {0.f, 0.f, 0.f, 0.f};
#pragma unroll
        for (int k4 = 0; k4 < 16; ++k4) {
            const float4 wr = *(const float4*)&s_wrT[o * 68 + k4 * 4];
            const float4 wo = *(const float4*)&s_woT[o * 68 + k4 * 4];
#pragma unroll
            for (int j = 0; j < 4; ++j) {
                const float4 xv = *(const float4*)&s_x[(ng * 4 + j) * 68 + k4 * 4];
                accr[j] = fmaf(xv.x, wr.x, fmaf(xv.y, wr.y, fmaf(xv.z, wr.z, fmaf(xv.w, wr.w, accr[j]))));
                acco[j] = fmaf(xv.x, wo.x, fmaf(xv.y, wo.y, fmaf(xv.z, wo.z, fmaf(xv.w, wo.w, acco[j]))));
            }
        }
#pragma unroll
        for (int j = 0; j < 4; ++j) {
            const int node = node0 + ng * 4 + j;
            if (node < n_nodes) {
                p1[(size_t)node * 16 + o] = accr[j];
                r1[(size_t)node * 16 + o] = acco[j] + s_b[o];
            }
        }
    } else {
        // ---- slot fill: 4 independent atomic chains per thread ----
        const int tid = ((int)blockIdx.x - tb) * 256 + t;
        const int e0 = tid * 4;
        if (e0 >= n_edges) return;
        int d[4], sr[4];
        int ne = 4;
        if (e0 + 3 < n_edges) {
            const int4 dv = *(const int4*)(dst + e0);
            const int4 sv = *(const int4*)(src + e0);
            d[0] = dv.x; d[1] = dv.y; d[2] = dv.z; d[3] = dv.w;
            sr[0] = sv.x; sr[1] = sv.y; sr[2] = sv.z; sr[3] = sv.w;
        } else {
            ne = n_edges - e0;
            for (int k = 0; k < ne; ++k) { d[k] = dst[e0 + k]; sr[k] = src[e0 + k]; }
        }
#pragma unroll
        for (int k = 0; k < 4; ++k) {
            if (k >= ne) break;
            const int pos = atomicAdd(&cnt[d[k]], 1);
            if (pos < SLOT) {
                slots[(size_t)d[k] * SLOT + pos] = sr[k];
            } else {   // exact fallback, expected never
                const int op = atomicAdd(ovf_n, 1);
                ovf_dst[op] = d[k];
                ovf_src[op] = sr[k];
            }
        }
    }
}

// ============ Gather + relu + folded layer-2 scalars + per-graph u/count bins ============
// 4 threads per node (q = float4 quarter). s[i]=relu(h1)@w2r ; T2 bins += relu(h1)@w2o
__global__ __launch_bounds__(256) void k_gather(
    const float* __restrict__ p1, const float* __restrict__ r1,
    const int* __restrict__ cnt, const int* __restrict__ slots,
    const int* __restrict__ ovf_n, const int* __restrict__ ovf_dst,
    const int* __restrict__ ovf_src,
    const int* __restrict__ batch,
    const float* __restrict__ W2rel, const float* __restrict__ W2root,
    const float* __restrict__ Wlin,
    float* __restrict__ s_out, float* __restrict__ T2, float* __restrict__ cntg,
    int n_nodes)
{
    __shared__ float s_w2r[16], s_w2o[16];
    __shared__ float s_T2[64], s_cnt[64];
    __shared__ int s_no;

    const int t = threadIdx.x;
    if (t < 16) {   // fold W2 through the linear head (16 FMAs each, trivial)
        float ar = 0.f, ao = 0.f;
#pragma unroll
        for (int o = 0; o < 16; ++o) {
            const float wl = Wlin[o];
            ar = fmaf(W2rel[t * 16 + o], wl, ar);
            ao = fmaf(W2root[t * 16 + o], wl, ao);
        }
        s_w2r[t] = ar; s_w2o[t] = ao;
    }
    if (t < 64) { s_T2[t] = 0.f; s_cnt[t] = 0.f; }
    if (t == 0) s_no = *ovf_n;
    __syncthreads();

    const int idx = blockIdx.x * 256 + t;
    const int node = idx >> 2, q = idx & 3;
    if (node < n_nodes) {
        float4 h = *(const float4*)(r1 + (size_t)node * 16 + q * 4);
        const int c = min(cnt[node], SLOT);
        const int base = node * SLOT;
        int j = 0;
        for (; j + 2 <= c; j += 2) {
            const int s0 = slots[base + j], s1 = slots[base + j + 1];
            const float4 a = *(const float4*)(p1 + (size_t)s0 * 16 + q * 4);
            const float4 b = *(const float4*)(p1 + (size_t)s1 * 16 + q * 4);
            h.x += a.x; h.y += a.y; h.z += a.z; h.w += a.w;
            h.x += b.x; h.y += b.y; h.z += b.z; h.w += b.w;
        }
        if (j < c) {
            const int s0 = slots[base + j];
            const float4 a = *(const float4*)(p1 + (size_t)s0 * 16 + q * 4);
            h.x += a.x; h.y += a.y; h.z += a.z; h.w += a.w;
        }
        // overflow list (s_no expected 0)
        for (int ov = 0; ov < s_no; ++ov) {
            if (ovf_dst[ov] == node) {
                const float4 a = *(const float4*)(p1 + (size_t)ovf_src[ov] * 16 + q * 4);
                h.x += a.x; h.y += a.y; h.z += a.z; h.w += a.w;
            }
        }
        // relu
        h.x = fmaxf(h.x, 0.f); h.y = fmaxf(h.y, 0.f);
        h.z = fmaxf(h.z, 0.f); h.w = fmaxf(h.w, 0.f);
        // partial dots with folded vectors
        const float4 wr = *(const float4*)&s_w2r[q * 4];
        const float4 wo = *(const float4*)&s_w2o[q * 4];
        float ps = h.x * wr.x + h.y * wr.y + h.z * wr.z + h.w * wr.w;
        float pu = h.x * wo.x + h.y * wo.y + h.z * wo.z + h.w * wo.w;
        // reduce across the 4 q-lanes (adjacent lanes in wave)
        ps += __shfl_xor(ps, 1); ps += __shfl_xor(ps, 2);
        pu += __shfl_xor(pu, 1); pu += __shfl_xor(pu, 2);
        if (q == 0) {
            s_out[node] = ps;
            const int g = batch[node];
            atomicAdd(&s_T2[g], pu);
            atomicAdd(&s_cnt[g], 1.f);
        }
    }
    __syncthreads();
    if (t < 64) {
        if (s_T2[t] != 0.f) atomicAdd(&T2[t], s_T2[t]);
        if (s_cnt[t] != 0.f) atomicAdd(&cntg[t], s_cnt[t]);
    }
}

// ============ Edge pass: T1[batch[dst]] += s[src], LDS-privatized, 4 edges/thread ============
__global__ __launch_bounds__(256) void k_edgeT1(
    const int* __restrict__ src, const int* __restrict__ dst,
    const int* __restrict__ batch, const float* __restrict__ s_in,
    float* __restrict__ T1, int n_edges)
{
    __shared__ float bins[64];
    const int t = threadIdx.x;
    if (t < 64) bins[t] = 0.f;
    __syncthreads();

    const int e0 = (blockIdx.x * 256 + t) * 4;
    if (e0 < n_edges) {
        int d[4], sr[4];
        int ne = 4;
        if (e0 + 3 < n_edges) {
            const int4 dv = *(const int4*)(dst + e0);
            const int4 sv = *(const int4*)(src + e0);
            d[0] = dv.x; d[1] = dv.y; d[2] = dv.z; d[3] = dv.w;
            sr[0] = sv.x; sr[1] = sv.y; sr[2] = sv.z; sr[3] = sv.w;
        } else {
            ne = n_edges - e0;
            for (int k = 0; k < ne; ++k) { d[k] = dst[e0 + k]; sr[k] = src[e0 + k]; }
        }
        int g[4]; float v[4];
#pragma unroll
        for (int k = 0; k < 4; ++k) {
            if (k >= ne) break;
            g[k] = batch[d[k]];
            v[k] = s_in[sr[k]];
        }
#pragma unroll
        for (int k = 0; k < 4; ++k) {
            if (k >= ne) break;
            atomicAdd(&bins[g[k]], v[k]);
        }
    }
    __syncthreads();
    if (t < 64 && bins[t] != 0.f) atomicAdd(&T1[t], bins[t]);
}

// ============ Head: out[g] = (T1+T2)/c + b2.Wlin + blin ============
__global__ void k_finalize(
    const float* __restrict__ T1, const float* __restrict__ T2,
    const float* __restrict__ cntg, const float* __restrict__ b2,
    const float* __restrict__ Wlin, const float* __restrict__ blin,
    float* __restrict__ out, int n_graphs)
{
    const int g = threadIdx.x;
    if (g >= n_graphs) return;
    float cb = 0.f;
#pragma unroll
    for (int o = 0; o < 16; ++o) cb = fmaf(b2[o], Wlin[o], cb);
    const float c = fmaxf(cntg[g], 1.f);
    out[g] = (T1[g] + T2[g]) / c + cb + blin[0];
}

extern "C" void kernel_launch(void* const* d_in, const int* in_sizes, int n_in,
                              void* d_out, int out_size, void* d_ws, size_t ws_size,
                              hipStream_t stream) {
    const float* x       = (const float*)d_in[0];
    const int*   ei      = (const int*)d_in[1];
    const int*   batch   = (const int*)d_in[2];
    const float* W1_rel  = (const float*)d_in[3];
    const float* W1_root = (const float*)d_in[4];
    const float* b1      = (const float*)d_in[5];
    const float* W2_rel  = (const float*)d_in[6];
    const float* W2_root = (const float*)d_in[7];
    const float* b2      = (const float*)d_in[8];
    const float* Wlin    = (const float*)d_in[9];
    const float* blin    = (const float*)d_in[10];
    float* out = (float*)d_out;

    const int N = in_sizes[0] / 64;
    const int E = in_sizes[1] / 2;
    const int G = out_size;

    const int* src = ei;
    const int* dst = ei + E;

    // ---- workspace layout (floats/ints, all 4B; float4 regions 16B-aligned) ----
    float* ws      = (float*)d_ws;
    float* p1      = ws;                               // N*16
    float* r1      = p1 + (size_t)N * 16;              // N*16
    int*   cnt     = (int*)(r1 + (size_t)N * 16);      // N      -- memset start
    int*   ovf_n   = cnt + N;                          // 1
    float* T1      = (float*)(ovf_n + 1);              // G
    float* T2      = T1 + G;                           // G
    float* cntg    = T2 + G;                           // G      -- memset end
    int*   slots   = (int*)(cntg + G);                 // N*SLOT
    int*   ovf_dst = slots + (size_t)N * SLOT;         // E
    int*   ovf_src = ovf_dst + E;                      // E
    float* s_buf   = (float*)(ovf_src + E);            // N

    hipMemsetAsync(cnt, 0, (size_t)(N + 1 + 3 * G) * sizeof(int), stream);

    const int tb = (N + 63) / 64;            // transform blocks
    const int fb = (E + 1023) / 1024;        // fill blocks (4 edges/thread)
    const int gb = (N * 4 + 255) / 256;      // gather blocks
    const int ebt = (E + 1023) / 1024;       // edgeT1 blocks

    k_phase1 <<<tb + fb, 256, 0, stream>>>(x, W1_rel, W1_root, b1, src, dst,
                                           p1, r1, cnt, slots, ovf_n, ovf_dst, ovf_src,
                                           N, E, tb);
    k_gather <<<gb, 256, 0, stream>>>(p1, r1, cnt, slots, ovf_n, ovf_dst, ovf_src,
                                      batch, W2_rel, W2_root, Wlin,
                                      s_buf, T2, cntg, N);
    k_edgeT1 <<<ebt, 256, 0, stream>>>(src, dst, batch, s_buf, T1, E);
    k_finalize<<<1, 64, 0, stream>>>(T1, T2, cntg, b2, Wlin, blin, out, G);
}